// Round 7
// baseline (442.841 us; speedup 1.0000x reference)
//
#include <hip/hip_runtime.h>

#define NEG_SLOPE 0.2f

typedef __attribute__((ext_vector_type(8))) short bf16x8;
typedef __attribute__((ext_vector_type(4))) float f32x4;

__device__ inline unsigned short f2bf(float f) {
    unsigned int u = __float_as_uint(f);
    unsigned int r = (u + 0x7fffu + ((u >> 16) & 1u)) >> 16;
    return (unsigned short)r;
}

// ---------------- prep: f32 -> bf16 (vectorized) ----------------
__global__ void xprep_k(const float* __restrict__ in, unsigned short* __restrict__ out, int count4) {
    int i = blockIdx.x * blockDim.x + threadIdx.x;
    if (i >= count4) return;
    float4 v = ((const float4*)in)[i];
    ushort4 o;
    o.x = f2bf(v.x); o.y = f2bf(v.y); o.z = f2bf(v.z); o.w = f2bf(v.w);
    ((ushort4*)out)[i] = o;
}

// ---------------- prep: W[K][NOUT] f32 -> Wl[kc][n] chunk-major bf16 ----------------
__global__ void wprep_k(const float* __restrict__ W, unsigned short* __restrict__ Wl, int K, int NOUT) {
    int gid = blockIdx.x * blockDim.x + threadIdx.x;
    int total = (K / 8) * NOUT;
    if (gid >= total) return;
    int kc = gid / NOUT, nn = gid % NOUT;
    unsigned int w[4];
#pragma unroll
    for (int p = 0; p < 4; p++) {
        unsigned int lo = f2bf(W[(size_t)(kc * 8 + 2 * p + 0) * NOUT + nn]);
        unsigned int hi = f2bf(W[(size_t)(kc * 8 + 2 * p + 1) * NOUT + nn]);
        w[p] = lo | (hi << 16);
    }
    uint4 o; o.x = w[0]; o.y = w[1]; o.z = w[2]; o.w = w[3];
    ((uint4*)Wl)[gid] = o;
}

// ---------------- global max |v| (upper bound for softmax shift) ----------------
__global__ void gmax_k(const float* __restrict__ v, unsigned int* __restrict__ out, int count4) {
    float m = 0.f;
    for (int i = blockIdx.x * blockDim.x + threadIdx.x; i < count4; i += gridDim.x * blockDim.x) {
        float4 a = ((const float4*)v)[i];
        m = fmaxf(m, fmaxf(fmaxf(fabsf(a.x), fabsf(a.y)), fmaxf(fabsf(a.z), fabsf(a.w))));
    }
    for (int off = 1; off < 64; off <<= 1) m = fmaxf(m, __shfl_xor(m, off));
    __shared__ float red[4];
    int lane = threadIdx.x & 63, wid = threadIdx.x >> 6;
    if (lane == 0) red[wid] = m;
    __syncthreads();
    if (threadIdx.x == 0) {
        float mm = fmaxf(fmaxf(red[0], red[1]), fmaxf(red[2], red[3]));
        atomicMax(out, __float_as_uint(mm));   // all values >= 0: uint order == float order
    }
}

// ---------------- CSR build ----------------
__global__ void hist_k(const int* __restrict__ ei, int* __restrict__ cnt, int Eo, int Eext) {
    int e = blockIdx.x * blockDim.x + threadIdx.x;
    if (e >= Eext) return;
    int dv = (e < Eo) ? ei[Eo + e] : (e - Eo);
    atomicAdd(&cnt[dv], 1);
}

__global__ __launch_bounds__(256) void scan1_k(const int* __restrict__ cnt, int* __restrict__ rowptr,
                                               int* __restrict__ bsum, int n) {
    __shared__ int ts[256];
    int tid = threadIdx.x;
    int base = blockIdx.x * 1024 + tid * 4;
    int v0 = (base + 0 < n) ? cnt[base + 0] : 0;
    int v1 = (base + 1 < n) ? cnt[base + 1] : 0;
    int v2 = (base + 2 < n) ? cnt[base + 2] : 0;
    int v3 = (base + 3 < n) ? cnt[base + 3] : 0;
    int e1 = v0, e2 = e1 + v1, e3 = e2 + v2, tot = e3 + v3;
    ts[tid] = tot;
    __syncthreads();
    for (int off = 1; off < 256; off <<= 1) {
        int x = (tid >= off) ? ts[tid - off] : 0;
        __syncthreads();
        ts[tid] += x;
        __syncthreads();
    }
    int excl = ts[tid] - tot;
    if (base + 0 < n) rowptr[base + 0] = excl;
    if (base + 1 < n) rowptr[base + 1] = excl + e1;
    if (base + 2 < n) rowptr[base + 2] = excl + e2;
    if (base + 3 < n) rowptr[base + 3] = excl + e3;
    if (tid == 255) bsum[blockIdx.x] = ts[255];
}

__global__ void scan2_k(int* __restrict__ bsum, int nb) {
    if (threadIdx.x == 0 && blockIdx.x == 0) {
        int run = 0;
        for (int i = 0; i < nb; i++) { int t = bsum[i]; bsum[i] = run; run += t; }
    }
}

__global__ void scan3_k(int* __restrict__ rowptr, int* __restrict__ cursors,
                        const int* __restrict__ bsum, int n) {
    int gid = blockIdx.x * blockDim.x + threadIdx.x;
    if (gid >= n) return;
    int v = rowptr[gid] + bsum[gid >> 10];
    rowptr[gid] = v;
    cursors[gid] = v;
}

__global__ void scatter_k(const int* __restrict__ ei, int* __restrict__ cursors,
                          int* __restrict__ csr, int Eo, int Eext) {
    int e = blockIdx.x * blockDim.x + threadIdx.x;
    if (e >= Eext) return;
    int dv = (e < Eo) ? ei[Eo + e] : (e - Eo);
    int idx = atomicAdd(&cursors[dv], 1);
    csr[idx] = e;
}

__global__ void sort_k(const int* __restrict__ rowptr, const int* __restrict__ cnt,
                       int* __restrict__ csr, const int* __restrict__ ei,
                       int* __restrict__ csr_src, int n, int Eo) {
    int node = blockIdx.x * blockDim.x + threadIdx.x;
    if (node >= n) return;
    int ro = rowptr[node], deg = cnt[node];
    for (int i = 1; i < deg; i++) {
        int key = csr[ro + i];
        int j = i - 1;
        while (j >= 0 && csr[ro + j] > key) { csr[ro + j + 1] = csr[ro + j]; j--; }
        csr[ro + j + 1] = key;
    }
    for (int i = 0; i < deg; i++) {
        int eid = csr[ro + i];
        csr_src[ro + i] = (eid < Eo) ? ei[eid] : node;
    }
}

// ---------------- MFMA GEMM (bf16 in head-major, bf16 out head-major) + fused scores ----------------
// Input Xb: [HIN][M][CPH*8ch] head-major (CPH chunks of 8 bf16 per head); L1 uses HIN=1 (row-major).
// Output Hb: [NOUT/32][M][32ch] head-major. Scores esrc/edst: [Hh][M].
template<int K, int NOUT, int Hh, int CPH>
__global__ __launch_bounds__(256) void gemm_mfma(const unsigned short* __restrict__ Xb,
                                                 const unsigned short* __restrict__ Wl,
                                                 const float* __restrict__ As,
                                                 const float* __restrict__ Ad,
                                                 unsigned short* __restrict__ Hb,
                                                 float* __restrict__ esrc,
                                                 float* __restrict__ edst, int M) {
    constexpr int NT    = NOUT / 16;
    constexpr int TP    = (NT < 8) ? NT : 8;
    constexpr int NPASS = NT / TP;
    constexpr int HPP   = (TP * 16) / 32;

    __shared__ unsigned short wlds[K * NOUT];
    {
        const uint4* src = (const uint4*)Wl;
        uint4* dst = (uint4*)wlds;
        for (int i = threadIdx.x; i < K * NOUT / 8; i += 256) dst[i] = src[i];
    }
    __syncthreads();

    const int lane = threadIdx.x & 63;
    const int wid  = threadIdx.x >> 6;
    const int l15  = lane & 15;
    const int g4   = lane >> 4;
    const int m0   = blockIdx.x * 128 + wid * 32;
    const int m_s[2] = { m0 + l15, m0 + 16 + l15 };
    const int mi[2]  = { min(m_s[0], M - 1), min(m_s[1], M - 1) };

    const bf16x8* xb8 = (const bf16x8*)Xb;
    const bf16x8* wl8 = (const bf16x8*)wlds;

    for (int pass = 0; pass < NPASS; ++pass) {
        f32x4 acc[TP][2];
#pragma unroll
        for (int tt = 0; tt < TP; ++tt)
#pragma unroll
            for (int s = 0; s < 2; ++s) acc[tt][s] = (f32x4)0.f;

        for (int ks = 0; ks < K / 32; ++ks) {
            int kc = ks * 4 + g4;
            size_t a0i = (size_t)(kc / CPH) * M * CPH + (size_t)mi[0] * CPH + (kc % CPH);
            size_t a1i = (size_t)(kc / CPH) * M * CPH + (size_t)mi[1] * CPH + (kc % CPH);
            bf16x8 a0 = xb8[a0i];
            bf16x8 a1 = xb8[a1i];
#pragma unroll
            for (int tt = 0; tt < TP; ++tt) {
                int nn = (pass * TP + tt) * 16 + l15;
                bf16x8 b = wl8[kc * NOUT + nn];
                acc[tt][0] = __builtin_amdgcn_mfma_f32_16x16x32_bf16(b, a0, acc[tt][0], 0, 0, 0);
                acc[tt][1] = __builtin_amdgcn_mfma_f32_16x16x32_bf16(b, a1, acc[tt][1], 0, 0, 0);
            }
        }

        float s1[2][HPP], s2[2][HPP];
#pragma unroll
        for (int s = 0; s < 2; ++s)
#pragma unroll
            for (int hh = 0; hh < HPP; ++hh) { s1[s][hh] = 0.f; s2[s][hh] = 0.f; }

#pragma unroll
        for (int tt = 0; tt < TP; ++tt) {
            int t  = pass * TP + tt;
            int ch = t * 16 + g4 * 4;              // global output channel
            int ho = ch >> 5, chw = ch & 31;       // head-major placement
            float4 asv = *(const float4*)(As + ch);
            float4 adv = *(const float4*)(Ad + ch);
            int hh = tt >> 1;
#pragma unroll
            for (int s = 0; s < 2; ++s) {
                f32x4 a = acc[tt][s];
                s1[s][hh] += a[0] * asv.x + a[1] * asv.y + a[2] * asv.z + a[3] * asv.w;
                s2[s][hh] += a[0] * adv.x + a[1] * adv.y + a[2] * adv.z + a[3] * adv.w;
                int m = m_s[s];
                if (m < M) {
                    ushort4 o;
                    o.x = f2bf(a[0]); o.y = f2bf(a[1]); o.z = f2bf(a[2]); o.w = f2bf(a[3]);
                    *(ushort4*)(Hb + ((size_t)ho * M + m) * 32 + chw) = o;
                }
            }
        }
#pragma unroll
        for (int s = 0; s < 2; ++s) {
            int m = m_s[s];
#pragma unroll
            for (int hh = 0; hh < HPP; ++hh) {
                float p1 = s1[s][hh], p2 = s2[s][hh];
                p1 += __shfl_xor(p1, 16); p1 += __shfl_xor(p1, 32);
                p2 += __shfl_xor(p2, 16); p2 += __shfl_xor(p2, 32);
                if (g4 == 0 && m < M) {
                    int h = pass * HPP + hh;
                    esrc[(size_t)h * M + m] = p1;
                    edst[(size_t)h * M + m] = p2;
                }
            }
        }
    }
}

// ---------------- head-sliced fused softmax + gather-aggregate ----------------
__device__ inline void acc_bf8(float* acc, float a, uint4 p) {
    unsigned int u[4] = {p.x, p.y, p.z, p.w};
#pragma unroll
    for (int w = 0; w < 4; w++) {
        float lo = __uint_as_float(u[w] << 16);
        float hi = __uint_as_float(u[w] & 0xffff0000u);
        acc[2 * w + 0] += a * lo;
        acc[2 * w + 1] += a * hi;
    }
}

// One head-slice (32 ch, n x 64B table) per block-range; 4 lanes/node.
// exp computed once per edge by lane `sub`, exchanged via shfl_xor.
template<bool PRED>
__global__ __launch_bounds__(256) void aggr_sliced(const int* __restrict__ rowptr, const int* __restrict__ cnt,
                                                   const int* __restrict__ csr_src,
                                                   const float* __restrict__ esrc, const float* __restrict__ edst,
                                                   const unsigned int* __restrict__ gmaxb,
                                                   const unsigned short* __restrict__ Hb,
                                                   const float* __restrict__ bias,
                                                   unsigned short* __restrict__ OutB,
                                                   float* __restrict__ psrc, float* __restrict__ pdst,
                                                   const float* __restrict__ Wp, int n, int nbph) {
    int head = blockIdx.x / nbph;
    int node = (blockIdx.x % nbph) * 64 + (threadIdx.x >> 2);
    if (node >= n) return;
    int sub = threadIdx.x & 3;

    const float* esr = esrc + (size_t)head * n;
    float ed = edst[(size_t)head * n + node];
    float g  = __uint_as_float(*gmaxb);
    float ub = g + ed; ub = (ub >= 0.f) ? ub : NEG_SLOPE * ub;   // >= max over edges
    int ro = rowptr[node], deg = cnt[node];
    const unsigned short* hb = Hb + (size_t)head * n * 32;

    float s = 0.f;
    float acc[8];
#pragma unroll
    for (int c = 0; c < 8; c++) acc[c] = 0.f;

    int j = 0;
    for (; j + 4 <= deg; j += 4) {
        int ssel = csr_src[ro + j + sub];
        float v = esr[ssel] + ed;
        v = (v >= 0.f) ? v : NEG_SLOPE * v;
        float pa = __expf(v - ub);
        float pb = __shfl_xor(pa, 1);  int sb = __shfl_xor(ssel, 1);
        float pc = __shfl_xor(pa, 2);  int sc = __shfl_xor(ssel, 2);
        float pd = __shfl_xor(pb, 2);  int sd = __shfl_xor(sb, 2);
        uint4 q0 = *(const uint4*)(hb + (size_t)ssel * 32 + sub * 8);
        uint4 q1 = *(const uint4*)(hb + (size_t)sb   * 32 + sub * 8);
        uint4 q2 = *(const uint4*)(hb + (size_t)sc   * 32 + sub * 8);
        uint4 q3 = *(const uint4*)(hb + (size_t)sd   * 32 + sub * 8);
        s += pa + pb + pc + pd;
        acc_bf8(acc, pa, q0);
        acc_bf8(acc, pb, q1);
        acc_bf8(acc, pc, q2);
        acc_bf8(acc, pd, q3);
    }
    for (; j < deg; j++) {
        int sv = csr_src[ro + j];
        float v = esr[sv] + ed;
        v = (v >= 0.f) ? v : NEG_SLOPE * v;
        float p = __expf(v - ub);
        uint4 q = *(const uint4*)(hb + (size_t)sv * 32 + sub * 8);
        s += p;
        acc_bf8(acc, p, q);
    }

    float inv = 1.f / (s + 1e-16f);

    if (PRED) {
        float d1 = 0.f, d2 = 0.f;
#pragma unroll
        for (int c = 0; c < 8; c++) {
            float v = acc[c] * inv + bias[sub * 8 + c];
            v = v > 0.f ? v : 0.f;
            d1 += v * Wp[sub * 8 + c];
            d2 += v * Wp[32 + sub * 8 + c];
        }
        d1 += __shfl_xor(d1, 1); d1 += __shfl_xor(d1, 2);
        d2 += __shfl_xor(d2, 1); d2 += __shfl_xor(d2, 2);
        if (sub == 0) {
            psrc[node] = d1;
            pdst[node] = d2;
        }
    } else {
        const float* bslice = bias + head * 32 + sub * 8;
        uint4 o;
        unsigned int* op = (unsigned int*)&o;
#pragma unroll
        for (int w = 0; w < 4; w++) {
            float va = acc[2 * w + 0] * inv + bslice[2 * w + 0];
            float vb = acc[2 * w + 1] * inv + bslice[2 * w + 1];
            va = va > 0.f ? va : 0.f;
            vb = vb > 0.f ? vb : 0.f;
            op[w] = (unsigned int)f2bf(va) | ((unsigned int)f2bf(vb) << 16);
        }
        *(uint4*)(OutB + ((size_t)head * n + node) * 32 + sub * 8) = o;
    }
}

// ---------------- rank-1 edge predictor ----------------
__global__ void predict2_k(const int* __restrict__ ei, const float* __restrict__ psrc,
                           const float* __restrict__ pdst, const float* __restrict__ bp,
                           float* __restrict__ out, int Eo) {
    int e = blockIdx.x * blockDim.x + threadIdx.x;
    if (e >= Eo) return;
    float acc = psrc[ei[e]] + pdst[ei[Eo + e]] + bp[0];
    float sg = 1.f / (1.f + __expf(-acc));
    out[e] = sg * 4.f + 1.f;
}

extern "C" void kernel_launch(void* const* d_in, const int* in_sizes, int n_in,
                              void* d_out, int out_size, void* d_ws, size_t ws_size,
                              hipStream_t stream) {
    const float* x   = (const float*)d_in[0];
    const int*   ei  = (const int*)  d_in[1];
    const float* W1  = (const float*)d_in[2];
    const float* as1 = (const float*)d_in[3];
    const float* ad1 = (const float*)d_in[4];
    const float* b1  = (const float*)d_in[5];
    const float* W2  = (const float*)d_in[6];
    const float* as2 = (const float*)d_in[7];
    const float* ad2 = (const float*)d_in[8];
    const float* b2  = (const float*)d_in[9];
    const float* W3  = (const float*)d_in[10];
    const float* as3 = (const float*)d_in[11];
    const float* ad3 = (const float*)d_in[12];
    const float* b3  = (const float*)d_in[13];
    const float* Wp  = (const float*)d_in[14];
    const float* bp  = (const float*)d_in[15];
    float* outp = (float*)d_out;

    const int n    = in_sizes[0] / 128;   // 50000
    const int Eo   = in_sizes[1] / 2;     // 800000
    const int Eext = Eo + n;              // 850000

    char* base = (char*)d_ws;
    unsigned short* hAb = (unsigned short*)base;   base += (size_t)n * 256 * 2;
    unsigned short* hBb = (unsigned short*)base;   base += (size_t)n * 256 * 2;
    unsigned short* Xb  = (unsigned short*)base;   base += (size_t)n * 128 * 2;
    unsigned short* Wl1 = (unsigned short*)base;   base += (size_t)128 * 256 * 2;
    unsigned short* Wl2 = (unsigned short*)base;   base += (size_t)256 * 128 * 2;
    unsigned short* Wl3 = (unsigned short*)base;   base += (size_t)128 * 32 * 2;
    float* esrc   = (float*)base;                  base += (size_t)n * 8 * 4;
    float* edst   = (float*)base;                  base += (size_t)n * 8 * 4;
    float* psrc   = (float*)base;                  base += (size_t)n * 4;
    float* pdst   = (float*)base;                  base += (size_t)n * 4;
    unsigned int* gmaxb = (unsigned int*)base;     base += 16;
    int* cnt      = (int*)base;                    base += (size_t)n * 4;
    int* rowptr   = (int*)base;                    base += (size_t)n * 4;
    int* cursors  = (int*)base;                    base += (size_t)n * 4;
    int* csr      = (int*)base;                    base += (size_t)Eext * 4;
    int* csr_src  = (int*)base;                    base += (size_t)Eext * 4;
    int* bsum     = (int*)base;

    const int TB = 256;
    auto nb = [](int tot, int tb) { return (tot + tb - 1) / tb; };
    const int nbph = (n + 63) / 64;

    // ---------------- CSR build (dst-sorted) ----------------
    hipMemsetAsync(cnt, 0, (size_t)n * 4, stream);
    hipMemsetAsync(gmaxb, 0, 16, stream);
    hist_k<<<nb(Eext, TB), TB, 0, stream>>>(ei, cnt, Eo, Eext);
    int nChunks = (n + 1023) / 1024;
    scan1_k<<<nChunks, 256, 0, stream>>>(cnt, rowptr, bsum, n);
    scan2_k<<<1, 64, 0, stream>>>(bsum, nChunks);
    scan3_k<<<nb(n, TB), TB, 0, stream>>>(rowptr, cursors, bsum, n);
    scatter_k<<<nb(Eext, TB), TB, 0, stream>>>(ei, cursors, csr, Eo, Eext);
    sort_k<<<nb(n, TB), TB, 0, stream>>>(rowptr, cnt, csr, ei, csr_src, n, Eo);

    // ---------------- prep: bf16 conversions ----------------
    xprep_k<<<nb(n * 128 / 4, TB), TB, 0, stream>>>(x, Xb, n * 128 / 4);
    wprep_k<<<nb(16 * 256, TB), TB, 0, stream>>>(W1, Wl1, 128, 256);
    wprep_k<<<nb(32 * 128, TB), TB, 0, stream>>>(W2, Wl2, 256, 128);
    wprep_k<<<nb(16 * 32, TB), TB, 0, stream>>>(W3, Wl3, 128, 32);

    // ---------------- Layer 1: K=128, H=8 ----------------
    gemm_mfma<128, 256, 8, 16><<<nb(n, 128), 256, 0, stream>>>(Xb, Wl1, as1, ad1, hAb, esrc, edst, n);
    gmax_k<<<64, 256, 0, stream>>>(esrc, gmaxb + 0, n * 8 / 4);
    aggr_sliced<false><<<8 * nbph, 256, 0, stream>>>(rowptr, cnt, csr_src, esrc, edst, gmaxb + 0,
                                                     hAb, b1, hBb, nullptr, nullptr, nullptr, n, nbph);

    // ---------------- Layer 2: K=256, H=4 ----------------
    gemm_mfma<256, 128, 4, 4><<<nb(n, 128), 256, 0, stream>>>(hBb, Wl2, as2, ad2, hAb, esrc, edst, n);
    gmax_k<<<64, 256, 0, stream>>>(esrc, gmaxb + 1, n * 4 / 4);
    aggr_sliced<false><<<4 * nbph, 256, 0, stream>>>(rowptr, cnt, csr_src, esrc, edst, gmaxb + 1,
                                                     hAb, b2, hBb, nullptr, nullptr, nullptr, n, nbph);

    // ---------------- Layer 3: K=128, H=1 (fused rank-1 predictor dots) ----------------
    gemm_mfma<128, 32, 1, 4><<<nb(n, 128), 256, 0, stream>>>(hBb, Wl3, as3, ad3, hAb, esrc, edst, n);
    gmax_k<<<64, 256, 0, stream>>>(esrc, gmaxb + 2, n / 4);
    aggr_sliced<true><<<1 * nbph, 256, 0, stream>>>(rowptr, cnt, csr_src, esrc, edst, gmaxb + 2,
                                                    hAb, b3, nullptr, psrc, pdst, Wp, n, nbph);

    // ---------------- predictor ----------------
    predict2_k<<<nb(Eo, TB), TB, 0, stream>>>(ei, psrc, pdst, bp, outp, Eo);
}

// Round 8
// 388.903 us; speedup vs baseline: 1.1387x; 1.1387x over previous
//
#include <hip/hip_runtime.h>

#define NEG_SLOPE 0.2f

typedef __attribute__((ext_vector_type(8))) short bf16x8;
typedef __attribute__((ext_vector_type(4))) float f32x4;

__device__ inline unsigned short f2bf(float f) {
    unsigned int u = __float_as_uint(f);
    unsigned int r = (u + 0x7fffu + ((u >> 16) & 1u)) >> 16;
    return (unsigned short)r;
}

// ---------------- fused prep: x->bf16 and W1/W2/W3 -> chunk-major bf16 ----------------
__device__ inline void wprep_item(const float* __restrict__ W, unsigned short* __restrict__ Wl,
                                  int K, int NOUT, int item) {
    int kc = item / NOUT, nn = item % NOUT;
    unsigned int w[4];
#pragma unroll
    for (int p = 0; p < 4; p++) {
        unsigned int lo = f2bf(W[(size_t)(kc * 8 + 2 * p + 0) * NOUT + nn]);
        unsigned int hi = f2bf(W[(size_t)(kc * 8 + 2 * p + 1) * NOUT + nn]);
        w[p] = lo | (hi << 16);
    }
    uint4 o; o.x = w[0]; o.y = w[1]; o.z = w[2]; o.w = w[3];
    ((uint4*)Wl)[item] = o;
}

__global__ void prep_all_k(const float* __restrict__ x, unsigned short* __restrict__ Xb,
                           const float* __restrict__ W1, unsigned short* __restrict__ Wl1,
                           const float* __restrict__ W2, unsigned short* __restrict__ Wl2,
                           const float* __restrict__ W3, unsigned short* __restrict__ Wl3,
                           int nx4) {
    int gid = blockIdx.x * blockDim.x + threadIdx.x;
    if (gid < nx4) {
        float4 v = ((const float4*)x)[gid];
        ushort4 o;
        o.x = f2bf(v.x); o.y = f2bf(v.y); o.z = f2bf(v.z); o.w = f2bf(v.w);
        ((ushort4*)Xb)[gid] = o;
        return;
    }
    int r = gid - nx4;
    if (r < 4096) { wprep_item(W1, Wl1, 128, 256, r); return; }
    r -= 4096;
    if (r < 4096) { wprep_item(W2, Wl2, 256, 128, r); return; }
    r -= 4096;
    if (r < 512)  { wprep_item(W3, Wl3, 128, 32, r); }
}

// ---------------- CSR build ----------------
__global__ void hist_k(const int* __restrict__ ei, int* __restrict__ cnt, int Eo, int Eext) {
    int e = blockIdx.x * blockDim.x + threadIdx.x;
    if (e >= Eext) return;
    int dv = (e < Eo) ? ei[Eo + e] : (e - Eo);
    atomicAdd(&cnt[dv], 1);
}

__global__ __launch_bounds__(256) void scan1_k(const int* __restrict__ cnt, int* __restrict__ rowptr,
                                               int* __restrict__ bsum, int n) {
    __shared__ int ts[256];
    int tid = threadIdx.x;
    int base = blockIdx.x * 1024 + tid * 4;
    int v0 = (base + 0 < n) ? cnt[base + 0] : 0;
    int v1 = (base + 1 < n) ? cnt[base + 1] : 0;
    int v2 = (base + 2 < n) ? cnt[base + 2] : 0;
    int v3 = (base + 3 < n) ? cnt[base + 3] : 0;
    int e1 = v0, e2 = e1 + v1, e3 = e2 + v2, tot = e3 + v3;
    ts[tid] = tot;
    __syncthreads();
    for (int off = 1; off < 256; off <<= 1) {
        int x = (tid >= off) ? ts[tid - off] : 0;
        __syncthreads();
        ts[tid] += x;
        __syncthreads();
    }
    int excl = ts[tid] - tot;
    if (base + 0 < n) rowptr[base + 0] = excl;
    if (base + 1 < n) rowptr[base + 1] = excl + e1;
    if (base + 2 < n) rowptr[base + 2] = excl + e2;
    if (base + 3 < n) rowptr[base + 3] = excl + e3;
    if (tid == 255) bsum[blockIdx.x] = ts[255];
}

__global__ void scan2_k(int* __restrict__ bsum, int nb) {
    if (threadIdx.x == 0 && blockIdx.x == 0) {
        int run = 0;
        for (int i = 0; i < nb; i++) { int t = bsum[i]; bsum[i] = run; run += t; }
    }
}

__global__ void scan3_k(int* __restrict__ rowptr, int* __restrict__ cursors,
                        const int* __restrict__ bsum, int n) {
    int gid = blockIdx.x * blockDim.x + threadIdx.x;
    if (gid >= n) return;
    int v = rowptr[gid] + bsum[gid >> 10];
    rowptr[gid] = v;
    cursors[gid] = v;
}

__global__ void scatter_k(const int* __restrict__ ei, int* __restrict__ cursors,
                          int* __restrict__ csr, int Eo, int Eext) {
    int e = blockIdx.x * blockDim.x + threadIdx.x;
    if (e >= Eext) return;
    int dv = (e < Eo) ? ei[Eo + e] : (e - Eo);
    int idx = atomicAdd(&cursors[dv], 1);
    csr[idx] = e;
}

__global__ void sort_k(const int* __restrict__ rowptr, const int* __restrict__ cnt,
                       int* __restrict__ csr, const int* __restrict__ ei,
                       int* __restrict__ csr_src, int n, int Eo) {
    int node = blockIdx.x * blockDim.x + threadIdx.x;
    if (node >= n) return;
    int ro = rowptr[node], deg = cnt[node];
    for (int i = 1; i < deg; i++) {
        int key = csr[ro + i];
        int j = i - 1;
        while (j >= 0 && csr[ro + j] > key) { csr[ro + j + 1] = csr[ro + j]; j--; }
        csr[ro + j + 1] = key;
    }
    for (int i = 0; i < deg; i++) {
        int eid = csr[ro + i];
        csr_src[ro + i] = (eid < Eo) ? ei[eid] : node;
    }
}

// ---------------- MFMA GEMM (bf16 in, bf16 out) + fused scores + fused gmax ----------------
template<int K, int NOUT, int Hh>
__global__ __launch_bounds__(256) void gemm_mfma(const unsigned short* __restrict__ Xb,
                                                 const unsigned short* __restrict__ Wl,
                                                 const float* __restrict__ As,
                                                 const float* __restrict__ Ad,
                                                 unsigned short* __restrict__ Hb,
                                                 float* __restrict__ esrc,
                                                 float* __restrict__ edst,
                                                 unsigned int* __restrict__ gmaxb, int M) {
    constexpr int NT    = NOUT / 16;
    constexpr int TP    = (NT < 8) ? NT : 8;
    constexpr int NPASS = NT / TP;
    constexpr int NCH   = K / 8;
    constexpr int HPP   = (TP * 16) / 32;

    __shared__ unsigned short wlds[K * NOUT];
    {
        const uint4* src = (const uint4*)Wl;
        uint4* dst = (uint4*)wlds;
        for (int i = threadIdx.x; i < K * NOUT / 8; i += 256) dst[i] = src[i];
    }
    __syncthreads();

    const int lane = threadIdx.x & 63;
    const int wid  = threadIdx.x >> 6;
    const int l15  = lane & 15;
    const int g4   = lane >> 4;
    const int m0   = blockIdx.x * 128 + wid * 32;
    const int m_s[2] = { m0 + l15, m0 + 16 + l15 };
    const int mi[2]  = { min(m_s[0], M - 1), min(m_s[1], M - 1) };

    const bf16x8* xb8 = (const bf16x8*)Xb;
    const bf16x8* wl8 = (const bf16x8*)wlds;

    float gmx = 0.f;

    for (int pass = 0; pass < NPASS; ++pass) {
        f32x4 acc[TP][2];
#pragma unroll
        for (int tt = 0; tt < TP; ++tt)
#pragma unroll
            for (int s = 0; s < 2; ++s) acc[tt][s] = (f32x4)0.f;

        for (int ks = 0; ks < K / 32; ++ks) {
            int kc = ks * 4 + g4;
            bf16x8 a0 = xb8[(size_t)mi[0] * NCH + kc];
            bf16x8 a1 = xb8[(size_t)mi[1] * NCH + kc];
#pragma unroll
            for (int tt = 0; tt < TP; ++tt) {
                int nn = (pass * TP + tt) * 16 + l15;
                bf16x8 b = wl8[kc * NOUT + nn];
                acc[tt][0] = __builtin_amdgcn_mfma_f32_16x16x32_bf16(b, a0, acc[tt][0], 0, 0, 0);
                acc[tt][1] = __builtin_amdgcn_mfma_f32_16x16x32_bf16(b, a1, acc[tt][1], 0, 0, 0);
            }
        }

        float s1[2][HPP], s2[2][HPP];
#pragma unroll
        for (int s = 0; s < 2; ++s)
#pragma unroll
            for (int hh = 0; hh < HPP; ++hh) { s1[s][hh] = 0.f; s2[s][hh] = 0.f; }

#pragma unroll
        for (int tt = 0; tt < TP; ++tt) {
            int t  = pass * TP + tt;
            int ch = t * 16 + g4 * 4;
            float4 asv = *(const float4*)(As + ch);
            float4 adv = *(const float4*)(Ad + ch);
            int hh = tt >> 1;
#pragma unroll
            for (int s = 0; s < 2; ++s) {
                f32x4 a = acc[tt][s];
                s1[s][hh] += a[0] * asv.x + a[1] * asv.y + a[2] * asv.z + a[3] * asv.w;
                s2[s][hh] += a[0] * adv.x + a[1] * adv.y + a[2] * adv.z + a[3] * adv.w;
                int m = m_s[s];
                if (m < M) {
                    ushort4 o;
                    o.x = f2bf(a[0]); o.y = f2bf(a[1]); o.z = f2bf(a[2]); o.w = f2bf(a[3]);
                    *(ushort4*)(Hb + (size_t)m * NOUT + ch) = o;
                }
            }
        }
#pragma unroll
        for (int s = 0; s < 2; ++s) {
            int m = m_s[s];
#pragma unroll
            for (int hh = 0; hh < HPP; ++hh) {
                float p1 = s1[s][hh], p2 = s2[s][hh];
                p1 += __shfl_xor(p1, 16); p1 += __shfl_xor(p1, 32);
                p2 += __shfl_xor(p2, 16); p2 += __shfl_xor(p2, 32);
                gmx = fmaxf(gmx, fabsf(p1));
                if (g4 == 0 && m < M) {
                    int h = pass * HPP + hh;
                    esrc[m * Hh + h] = p1;
                    edst[m * Hh + h] = p2;
                }
            }
        }
    }

    // wave-reduce gmx, one atomicMax per wave (values >= 0: uint order == float order)
    gmx = fmaxf(gmx, __shfl_xor(gmx, 1));
    gmx = fmaxf(gmx, __shfl_xor(gmx, 2));
    gmx = fmaxf(gmx, __shfl_xor(gmx, 4));
    gmx = fmaxf(gmx, __shfl_xor(gmx, 8));
    if (lane == 0) atomicMax(gmaxb, __float_as_uint(gmx));
}

// ---------------- fused softmax(ub) + gather-aggregate ----------------
__device__ inline void acc_bf8(float* acc, float a, uint4 p) {
    unsigned int u[4] = {p.x, p.y, p.z, p.w};
#pragma unroll
    for (int w = 0; w < 4; w++) {
        float lo = __uint_as_float(u[w] << 16);
        float hi = __uint_as_float(u[w] & 0xffff0000u);
        acc[2 * w + 0] += a * lo;
        acc[2 * w + 1] += a * hi;
    }
}

template<int HC, int Hh, bool PRED>
__global__ __launch_bounds__(256) void aggr_fused(const int* __restrict__ rowptr, const int* __restrict__ cnt,
                                                  const int* __restrict__ csr_src,
                                                  const float* __restrict__ esrc, const float* __restrict__ edst,
                                                  const unsigned int* __restrict__ gmaxb,
                                                  const unsigned short* __restrict__ Hb,
                                                  const float* __restrict__ bias,
                                                  unsigned short* __restrict__ OutB,
                                                  float* __restrict__ psrc, float* __restrict__ pdst,
                                                  const float* __restrict__ Wp, int n) {
    constexpr int TPN = HC / 8;
    constexpr int NPB = 256 / TPN;
    int node = blockIdx.x * NPB + threadIdx.x / TPN;
    if (node >= n) return;
    int t = threadIdx.x % TPN;
    int h = t >> 2;
    int sub = t & 3;
    int ro = rowptr[node], deg = cnt[node];
    float ed = edst[node * Hh + h];
    float g  = __uint_as_float(*gmaxb);
    float ub = g + ed; ub = (ub >= 0.f) ? ub : NEG_SLOPE * ub;   // >= max_j leaky(esrc[j]+ed)

    float s = 0.f;
    float acc[8];
#pragma unroll
    for (int c = 0; c < 8; c++) acc[c] = 0.f;

    int j = 0;
    for (; j + 8 <= deg; j += 8) {
        int sx[8];
#pragma unroll
        for (int u = 0; u < 8; u++) sx[u] = csr_src[ro + j + u];
        float av[8];
#pragma unroll
        for (int u = 0; u < 8; u++) {
            float v = esrc[sx[u] * Hh + h] + ed;
            v = (v >= 0.f) ? v : NEG_SLOPE * v;
            av[u] = __expf(v - ub);
        }
        uint4 q[8];
#pragma unroll
        for (int u = 0; u < 8; u++) q[u] = *(const uint4*)(Hb + (size_t)sx[u] * HC + 8 * t);
#pragma unroll
        for (int u = 0; u < 8; u++) { s += av[u]; acc_bf8(acc, av[u], q[u]); }
    }
    for (; j + 4 <= deg; j += 4) {
        int sx[4];
#pragma unroll
        for (int u = 0; u < 4; u++) sx[u] = csr_src[ro + j + u];
        float av[4];
#pragma unroll
        for (int u = 0; u < 4; u++) {
            float v = esrc[sx[u] * Hh + h] + ed;
            v = (v >= 0.f) ? v : NEG_SLOPE * v;
            av[u] = __expf(v - ub);
        }
        uint4 q[4];
#pragma unroll
        for (int u = 0; u < 4; u++) q[u] = *(const uint4*)(Hb + (size_t)sx[u] * HC + 8 * t);
#pragma unroll
        for (int u = 0; u < 4; u++) { s += av[u]; acc_bf8(acc, av[u], q[u]); }
    }
    for (; j < deg; j++) {
        int s0 = csr_src[ro + j];
        float v0 = esrc[s0 * Hh + h] + ed;
        v0 = (v0 >= 0.f) ? v0 : NEG_SLOPE * v0;
        float a0 = __expf(v0 - ub);
        uint4 p0 = *(const uint4*)(Hb + (size_t)s0 * HC + 8 * t);
        s += a0;
        acc_bf8(acc, a0, p0);
    }

    float inv = 1.f / (s + 1e-16f);

    if (PRED) {
        float d1 = 0.f, d2 = 0.f;
#pragma unroll
        for (int c = 0; c < 8; c++) {
            float v = acc[c] * inv + bias[sub * 8 + c];
            v = v > 0.f ? v : 0.f;
            d1 += v * Wp[sub * 8 + c];
            d2 += v * Wp[32 + sub * 8 + c];
        }
        d1 += __shfl_xor(d1, 1); d1 += __shfl_xor(d1, 2);
        d2 += __shfl_xor(d2, 1); d2 += __shfl_xor(d2, 2);
        if (sub == 0) {
            psrc[node] = d1;
            pdst[node] = d2;
        }
    } else {
        uint4 o;
        unsigned int* op = (unsigned int*)&o;
#pragma unroll
        for (int w = 0; w < 4; w++) {
            float va = acc[2 * w + 0] * inv + bias[8 * t + 2 * w + 0];
            float vb = acc[2 * w + 1] * inv + bias[8 * t + 2 * w + 1];
            va = va > 0.f ? va : 0.f;
            vb = vb > 0.f ? vb : 0.f;
            op[w] = (unsigned int)f2bf(va) | ((unsigned int)f2bf(vb) << 16);
        }
        *(uint4*)(OutB + (size_t)node * HC + 8 * t) = o;
    }
}

// ---------------- rank-1 edge predictor ----------------
__global__ void predict2_k(const int* __restrict__ ei, const float* __restrict__ psrc,
                           const float* __restrict__ pdst, const float* __restrict__ bp,
                           float* __restrict__ out, int Eo) {
    int e = blockIdx.x * blockDim.x + threadIdx.x;
    if (e >= Eo) return;
    float acc = psrc[ei[e]] + pdst[ei[Eo + e]] + bp[0];
    float sg = 1.f / (1.f + __expf(-acc));
    out[e] = sg * 4.f + 1.f;
}

extern "C" void kernel_launch(void* const* d_in, const int* in_sizes, int n_in,
                              void* d_out, int out_size, void* d_ws, size_t ws_size,
                              hipStream_t stream) {
    const float* x   = (const float*)d_in[0];
    const int*   ei  = (const int*)  d_in[1];
    const float* W1  = (const float*)d_in[2];
    const float* as1 = (const float*)d_in[3];
    const float* ad1 = (const float*)d_in[4];
    const float* b1  = (const float*)d_in[5];
    const float* W2  = (const float*)d_in[6];
    const float* as2 = (const float*)d_in[7];
    const float* ad2 = (const float*)d_in[8];
    const float* b2  = (const float*)d_in[9];
    const float* W3  = (const float*)d_in[10];
    const float* as3 = (const float*)d_in[11];
    const float* ad3 = (const float*)d_in[12];
    const float* b3  = (const float*)d_in[13];
    const float* Wp  = (const float*)d_in[14];
    const float* bp  = (const float*)d_in[15];
    float* outp = (float*)d_out;

    const int n    = in_sizes[0] / 128;   // 50000
    const int Eo   = in_sizes[1] / 2;     // 800000
    const int Eext = Eo + n;              // 850000

    char* base = (char*)d_ws;
    unsigned short* hAb = (unsigned short*)base;   base += (size_t)n * 256 * 2;
    unsigned short* hBb = (unsigned short*)base;   base += (size_t)n * 256 * 2;
    unsigned short* Xb  = (unsigned short*)base;   base += (size_t)n * 128 * 2;
    unsigned short* Wl1 = (unsigned short*)base;   base += (size_t)128 * 256 * 2;
    unsigned short* Wl2 = (unsigned short*)base;   base += (size_t)256 * 128 * 2;
    unsigned short* Wl3 = (unsigned short*)base;   base += (size_t)128 * 32 * 2;
    float* esrc   = (float*)base;                  base += (size_t)n * 8 * 4;
    float* edst   = (float*)base;                  base += (size_t)n * 8 * 4;
    float* psrc   = (float*)base;                  base += (size_t)n * 4;
    float* pdst   = (float*)base;                  base += (size_t)n * 4;
    int* cnt      = (int*)base;                    base += (size_t)n * 4;
    unsigned int* gmaxb = (unsigned int*)base;     base += 16;      // zeroed with cnt
    int* rowptr   = (int*)base;                    base += (size_t)n * 4;
    int* cursors  = (int*)base;                    base += (size_t)n * 4;
    int* csr      = (int*)base;                    base += (size_t)Eext * 4;
    int* csr_src  = (int*)base;                    base += (size_t)Eext * 4;
    int* bsum     = (int*)base;

    const int TB = 256;
    auto nb = [](int tot, int tb) { return (tot + tb - 1) / tb; };

    // ---------------- CSR build (dst-sorted) + prep ----------------
    hipMemsetAsync(cnt, 0, (size_t)n * 4 + 16, stream);   // cnt + gmaxb
    hist_k<<<nb(Eext, TB), TB, 0, stream>>>(ei, cnt, Eo, Eext);
    int nChunks = (n + 1023) / 1024;
    scan1_k<<<nChunks, 256, 0, stream>>>(cnt, rowptr, bsum, n);
    scan2_k<<<1, 64, 0, stream>>>(bsum, nChunks);
    scan3_k<<<nb(n, TB), TB, 0, stream>>>(rowptr, cursors, bsum, n);
    scatter_k<<<nb(Eext, TB), TB, 0, stream>>>(ei, cursors, csr, Eo, Eext);
    sort_k<<<nb(n, TB), TB, 0, stream>>>(rowptr, cnt, csr, ei, csr_src, n, Eo);
    int prep_total = n * 32 + 4096 + 4096 + 512;
    prep_all_k<<<nb(prep_total, TB), TB, 0, stream>>>(x, Xb, W1, Wl1, W2, Wl2, W3, Wl3, n * 32);

    // ---------------- Layer 1: K=128, H=8, HC=256 ----------------
    gemm_mfma<128, 256, 8><<<nb(n, 128), 256, 0, stream>>>(Xb, Wl1, as1, ad1, hAb, esrc, edst, gmaxb + 0, n);
    aggr_fused<256, 8, false><<<nb(n * 32, TB), TB, 0, stream>>>(rowptr, cnt, csr_src, esrc, edst, gmaxb + 0,
                                                                 hAb, b1, hBb, nullptr, nullptr, nullptr, n);

    // ---------------- Layer 2: K=256, H=4, HC=128 ----------------
    gemm_mfma<256, 128, 4><<<nb(n, 128), 256, 0, stream>>>(hBb, Wl2, as2, ad2, hAb, esrc, edst, gmaxb + 1, n);
    aggr_fused<128, 4, false><<<nb(n * 16, TB), TB, 0, stream>>>(rowptr, cnt, csr_src, esrc, edst, gmaxb + 1,
                                                                 hAb, b2, hBb, nullptr, nullptr, nullptr, n);

    // ---------------- Layer 3: K=128, H=1, HC=32 (fused rank-1 predictor dots) ----------------
    gemm_mfma<128, 32, 1><<<nb(n, 128), 256, 0, stream>>>(hBb, Wl3, as3, ad3, hAb, esrc, edst, gmaxb + 2, n);
    aggr_fused<32, 1, true><<<nb(n * 4, TB), TB, 0, stream>>>(rowptr, cnt, csr_src, esrc, edst, gmaxb + 2,
                                                              hAb, b3, nullptr, psrc, pdst, Wp, n);

    // ---------------- predictor ----------------
    predict2_k<<<nb(Eo, TB), TB, 0, stream>>>(ei, psrc, pdst, bp, outp, Eo);
}

// Round 9
// 384.784 us; speedup vs baseline: 1.1509x; 1.0107x over previous
//
#include <hip/hip_runtime.h>

#define NEG_SLOPE 0.2f

typedef __attribute__((ext_vector_type(8))) short bf16x8;
typedef __attribute__((ext_vector_type(4))) float f32x4;

__device__ inline unsigned short f2bf(float f) {
    unsigned int u = __float_as_uint(f);
    unsigned int r = (u + 0x7fffu + ((u >> 16) & 1u)) >> 16;
    return (unsigned short)r;
}

// ---------------- fused prep: x->bf16 and W1/W2/W3 -> chunk-major bf16 ----------------
__device__ inline void wprep_item(const float* __restrict__ W, unsigned short* __restrict__ Wl,
                                  int K, int NOUT, int item) {
    int kc = item / NOUT, nn = item % NOUT;
    unsigned int w[4];
#pragma unroll
    for (int p = 0; p < 4; p++) {
        unsigned int lo = f2bf(W[(size_t)(kc * 8 + 2 * p + 0) * NOUT + nn]);
        unsigned int hi = f2bf(W[(size_t)(kc * 8 + 2 * p + 1) * NOUT + nn]);
        w[p] = lo | (hi << 16);
    }
    uint4 o; o.x = w[0]; o.y = w[1]; o.z = w[2]; o.w = w[3];
    ((uint4*)Wl)[item] = o;
}

__global__ void prep_all_k(const float* __restrict__ x, unsigned short* __restrict__ Xb,
                           const float* __restrict__ W1, unsigned short* __restrict__ Wl1,
                           const float* __restrict__ W2, unsigned short* __restrict__ Wl2,
                           const float* __restrict__ W3, unsigned short* __restrict__ Wl3,
                           int nx4) {
    int gid = blockIdx.x * blockDim.x + threadIdx.x;
    if (gid < nx4) {
        float4 v = ((const float4*)x)[gid];
        ushort4 o;
        o.x = f2bf(v.x); o.y = f2bf(v.y); o.z = f2bf(v.z); o.w = f2bf(v.w);
        ((ushort4*)Xb)[gid] = o;
        return;
    }
    int r = gid - nx4;
    if (r < 4096) { wprep_item(W1, Wl1, 128, 256, r); return; }
    r -= 4096;
    if (r < 4096) { wprep_item(W2, Wl2, 256, 128, r); return; }
    r -= 4096;
    if (r < 512)  { wprep_item(W3, Wl3, 128, 32, r); }
}

// ---------------- CSR build ----------------
__global__ void hist_k(const int* __restrict__ ei, int* __restrict__ cnt, int Eo, int Eext) {
    int e = blockIdx.x * blockDim.x + threadIdx.x;
    if (e >= Eext) return;
    int dv = (e < Eo) ? ei[Eo + e] : (e - Eo);
    atomicAdd(&cnt[dv], 1);
}

__global__ __launch_bounds__(256) void scan1_k(const int* __restrict__ cnt, int* __restrict__ rowptr,
                                               int* __restrict__ bsum, int n) {
    __shared__ int ts[256];
    int tid = threadIdx.x;
    int base = blockIdx.x * 1024 + tid * 4;
    int v0 = (base + 0 < n) ? cnt[base + 0] : 0;
    int v1 = (base + 1 < n) ? cnt[base + 1] : 0;
    int v2 = (base + 2 < n) ? cnt[base + 2] : 0;
    int v3 = (base + 3 < n) ? cnt[base + 3] : 0;
    int e1 = v0, e2 = e1 + v1, e3 = e2 + v2, tot = e3 + v3;
    ts[tid] = tot;
    __syncthreads();
    for (int off = 1; off < 256; off <<= 1) {
        int x = (tid >= off) ? ts[tid - off] : 0;
        __syncthreads();
        ts[tid] += x;
        __syncthreads();
    }
    int excl = ts[tid] - tot;
    if (base + 0 < n) rowptr[base + 0] = excl;
    if (base + 1 < n) rowptr[base + 1] = excl + e1;
    if (base + 2 < n) rowptr[base + 2] = excl + e2;
    if (base + 3 < n) rowptr[base + 3] = excl + e3;
    if (tid == 255) bsum[blockIdx.x] = ts[255];
}

__global__ void scan2_k(int* __restrict__ bsum, int nb) {
    if (threadIdx.x == 0 && blockIdx.x == 0) {
        int run = 0;
        for (int i = 0; i < nb; i++) { int t = bsum[i]; bsum[i] = run; run += t; }
    }
}

__global__ void scan3_k(int* __restrict__ rowptr, int* __restrict__ cursors,
                        const int* __restrict__ bsum, int n) {
    int gid = blockIdx.x * blockDim.x + threadIdx.x;
    if (gid >= n) return;
    int v = rowptr[gid] + bsum[gid >> 10];
    rowptr[gid] = v;
    cursors[gid] = v;
}

__global__ void scatter_k(const int* __restrict__ ei, int* __restrict__ cursors,
                          int* __restrict__ csr, int Eo, int Eext) {
    int e = blockIdx.x * blockDim.x + threadIdx.x;
    if (e >= Eext) return;
    int dv = (e < Eo) ? ei[Eo + e] : (e - Eo);
    int idx = atomicAdd(&cursors[dv], 1);
    csr[idx] = e;
}

__global__ void sort_k(const int* __restrict__ rowptr, const int* __restrict__ cnt,
                       int* __restrict__ csr, const int* __restrict__ ei,
                       int* __restrict__ csr_src, int n, int Eo) {
    int node = blockIdx.x * blockDim.x + threadIdx.x;
    if (node >= n) return;
    int ro = rowptr[node], deg = cnt[node];
    for (int i = 1; i < deg; i++) {
        int key = csr[ro + i];
        int j = i - 1;
        while (j >= 0 && csr[ro + j] > key) { csr[ro + j + 1] = csr[ro + j]; j--; }
        csr[ro + j + 1] = key;
    }
    for (int i = 0; i < deg; i++) {
        int eid = csr[ro + i];
        csr_src[ro + i] = (eid < Eo) ? ei[eid] : node;
    }
}

// ---------------- MFMA GEMM (bf16 in, bf16 out) + fused scores + fused gmax ----------------
template<int K, int NOUT, int Hh>
__global__ __launch_bounds__(256) void gemm_mfma(const unsigned short* __restrict__ Xb,
                                                 const unsigned short* __restrict__ Wl,
                                                 const float* __restrict__ As,
                                                 const float* __restrict__ Ad,
                                                 unsigned short* __restrict__ Hb,
                                                 float* __restrict__ esrc,
                                                 float* __restrict__ edst,
                                                 unsigned int* __restrict__ gmaxb, int M) {
    constexpr int NT    = NOUT / 16;
    constexpr int TP    = (NT < 8) ? NT : 8;
    constexpr int NPASS = NT / TP;
    constexpr int NCH   = K / 8;
    constexpr int HPP   = (TP * 16) / 32;

    __shared__ unsigned short wlds[K * NOUT];
    {
        const uint4* src = (const uint4*)Wl;
        uint4* dst = (uint4*)wlds;
        for (int i = threadIdx.x; i < K * NOUT / 8; i += 256) dst[i] = src[i];
    }
    __syncthreads();

    const int lane = threadIdx.x & 63;
    const int wid  = threadIdx.x >> 6;
    const int l15  = lane & 15;
    const int g4   = lane >> 4;
    const int m0   = blockIdx.x * 128 + wid * 32;
    const int m_s[2] = { m0 + l15, m0 + 16 + l15 };
    const int mi[2]  = { min(m_s[0], M - 1), min(m_s[1], M - 1) };

    const bf16x8* xb8 = (const bf16x8*)Xb;
    const bf16x8* wl8 = (const bf16x8*)wlds;

    float gmx = 0.f;

    for (int pass = 0; pass < NPASS; ++pass) {
        f32x4 acc[TP][2];
#pragma unroll
        for (int tt = 0; tt < TP; ++tt)
#pragma unroll
            for (int s = 0; s < 2; ++s) acc[tt][s] = (f32x4)0.f;

        for (int ks = 0; ks < K / 32; ++ks) {
            int kc = ks * 4 + g4;
            bf16x8 a0 = xb8[(size_t)mi[0] * NCH + kc];
            bf16x8 a1 = xb8[(size_t)mi[1] * NCH + kc];
#pragma unroll
            for (int tt = 0; tt < TP; ++tt) {
                int nn = (pass * TP + tt) * 16 + l15;
                bf16x8 b = wl8[kc * NOUT + nn];
                acc[tt][0] = __builtin_amdgcn_mfma_f32_16x16x32_bf16(b, a0, acc[tt][0], 0, 0, 0);
                acc[tt][1] = __builtin_amdgcn_mfma_f32_16x16x32_bf16(b, a1, acc[tt][1], 0, 0, 0);
            }
        }

        float s1[2][HPP], s2[2][HPP];
#pragma unroll
        for (int s = 0; s < 2; ++s)
#pragma unroll
            for (int hh = 0; hh < HPP; ++hh) { s1[s][hh] = 0.f; s2[s][hh] = 0.f; }

#pragma unroll
        for (int tt = 0; tt < TP; ++tt) {
            int t  = pass * TP + tt;
            int ch = t * 16 + g4 * 4;
            float4 asv = *(const float4*)(As + ch);
            float4 adv = *(const float4*)(Ad + ch);
            int hh = tt >> 1;
#pragma unroll
            for (int s = 0; s < 2; ++s) {
                f32x4 a = acc[tt][s];
                s1[s][hh] += a[0] * asv.x + a[1] * asv.y + a[2] * asv.z + a[3] * asv.w;
                s2[s][hh] += a[0] * adv.x + a[1] * adv.y + a[2] * adv.z + a[3] * adv.w;
                int m = m_s[s];
                if (m < M) {
                    ushort4 o;
                    o.x = f2bf(a[0]); o.y = f2bf(a[1]); o.z = f2bf(a[2]); o.w = f2bf(a[3]);
                    *(ushort4*)(Hb + (size_t)m * NOUT + ch) = o;
                }
            }
        }
#pragma unroll
        for (int s = 0; s < 2; ++s) {
            int m = m_s[s];
#pragma unroll
            for (int hh = 0; hh < HPP; ++hh) {
                float p1 = s1[s][hh], p2 = s2[s][hh];
                p1 += __shfl_xor(p1, 16); p1 += __shfl_xor(p1, 32);
                p2 += __shfl_xor(p2, 16); p2 += __shfl_xor(p2, 32);
                gmx = fmaxf(gmx, fabsf(p1));
                if (g4 == 0 && m < M) {
                    int h = pass * HPP + hh;
                    esrc[m * Hh + h] = p1;
                    edst[m * Hh + h] = p2;
                }
            }
        }
    }

    // wave-reduce gmx, one atomicMax per wave (values >= 0: uint order == float order)
    gmx = fmaxf(gmx, __shfl_xor(gmx, 1));
    gmx = fmaxf(gmx, __shfl_xor(gmx, 2));
    gmx = fmaxf(gmx, __shfl_xor(gmx, 4));
    gmx = fmaxf(gmx, __shfl_xor(gmx, 8));
    if (lane == 0) atomicMax(gmaxb, __float_as_uint(gmx));
}

// ---------------- fused softmax(ub) + gather-aggregate (unroll-4, low VGPR) ----------------
__device__ inline void acc_bf8(float* acc, float a, uint4 p) {
    unsigned int u[4] = {p.x, p.y, p.z, p.w};
#pragma unroll
    for (int w = 0; w < 4; w++) {
        float lo = __uint_as_float(u[w] << 16);
        float hi = __uint_as_float(u[w] & 0xffff0000u);
        acc[2 * w + 0] += a * lo;
        acc[2 * w + 1] += a * hi;
    }
}

template<int HC, int Hh, bool PRED>
__global__ __launch_bounds__(256) void aggr_fused(const int* __restrict__ rowptr, const int* __restrict__ cnt,
                                                  const int* __restrict__ csr_src,
                                                  const float* __restrict__ esrc, const float* __restrict__ edst,
                                                  const unsigned int* __restrict__ gmaxb,
                                                  const unsigned short* __restrict__ Hb,
                                                  const float* __restrict__ bias,
                                                  unsigned short* __restrict__ OutB,
                                                  float* __restrict__ psrc, float* __restrict__ pdst,
                                                  const float* __restrict__ Wp, int n) {
    constexpr int TPN = HC / 8;
    constexpr int NPB = 256 / TPN;
    int node = blockIdx.x * NPB + threadIdx.x / TPN;
    if (node >= n) return;
    int t = threadIdx.x % TPN;
    int h = t >> 2;
    int sub = t & 3;
    int ro = rowptr[node], deg = cnt[node];
    float ed = edst[node * Hh + h];
    float g  = __uint_as_float(*gmaxb);
    float ub = g + ed; ub = (ub >= 0.f) ? ub : NEG_SLOPE * ub;   // >= max_j leaky(esrc[j]+ed)

    float s = 0.f;
    float acc[8];
#pragma unroll
    for (int c = 0; c < 8; c++) acc[c] = 0.f;

    int j = 0;
    for (; j + 4 <= deg; j += 4) {
        int s0 = csr_src[ro + j + 0], s1 = csr_src[ro + j + 1];
        int s2 = csr_src[ro + j + 2], s3 = csr_src[ro + j + 3];
        float v0 = esrc[s0 * Hh + h] + ed, v1 = esrc[s1 * Hh + h] + ed;
        float v2 = esrc[s2 * Hh + h] + ed, v3 = esrc[s3 * Hh + h] + ed;
        v0 = (v0 >= 0.f) ? v0 : NEG_SLOPE * v0;
        v1 = (v1 >= 0.f) ? v1 : NEG_SLOPE * v1;
        v2 = (v2 >= 0.f) ? v2 : NEG_SLOPE * v2;
        v3 = (v3 >= 0.f) ? v3 : NEG_SLOPE * v3;
        float a0 = __expf(v0 - ub), a1 = __expf(v1 - ub);
        float a2 = __expf(v2 - ub), a3 = __expf(v3 - ub);
        uint4 p0 = *(const uint4*)(Hb + (size_t)s0 * HC + 8 * t);
        uint4 p1 = *(const uint4*)(Hb + (size_t)s1 * HC + 8 * t);
        uint4 p2 = *(const uint4*)(Hb + (size_t)s2 * HC + 8 * t);
        uint4 p3 = *(const uint4*)(Hb + (size_t)s3 * HC + 8 * t);
        s += a0 + a1 + a2 + a3;
        acc_bf8(acc, a0, p0);
        acc_bf8(acc, a1, p1);
        acc_bf8(acc, a2, p2);
        acc_bf8(acc, a3, p3);
    }
    for (; j < deg; j++) {
        int s0 = csr_src[ro + j];
        float v0 = esrc[s0 * Hh + h] + ed;
        v0 = (v0 >= 0.f) ? v0 : NEG_SLOPE * v0;
        float a0 = __expf(v0 - ub);
        uint4 p0 = *(const uint4*)(Hb + (size_t)s0 * HC + 8 * t);
        s += a0;
        acc_bf8(acc, a0, p0);
    }

    float inv = 1.f / (s + 1e-16f);

    if (PRED) {
        float d1 = 0.f, d2 = 0.f;
#pragma unroll
        for (int c = 0; c < 8; c++) {
            float v = acc[c] * inv + bias[sub * 8 + c];
            v = v > 0.f ? v : 0.f;
            d1 += v * Wp[sub * 8 + c];
            d2 += v * Wp[32 + sub * 8 + c];
        }
        d1 += __shfl_xor(d1, 1); d1 += __shfl_xor(d1, 2);
        d2 += __shfl_xor(d2, 1); d2 += __shfl_xor(d2, 2);
        if (sub == 0) {
            psrc[node] = d1;
            pdst[node] = d2;
        }
    } else {
        uint4 o;
        unsigned int* op = (unsigned int*)&o;
#pragma unroll
        for (int w = 0; w < 4; w++) {
            float va = acc[2 * w + 0] * inv + bias[8 * t + 2 * w + 0];
            float vb = acc[2 * w + 1] * inv + bias[8 * t + 2 * w + 1];
            va = va > 0.f ? va : 0.f;
            vb = vb > 0.f ? vb : 0.f;
            op[w] = (unsigned int)f2bf(va) | ((unsigned int)f2bf(vb) << 16);
        }
        *(uint4*)(OutB + (size_t)node * HC + 8 * t) = o;
    }
}

// ---------------- rank-1 edge predictor ----------------
__global__ void predict2_k(const int* __restrict__ ei, const float* __restrict__ psrc,
                           const float* __restrict__ pdst, const float* __restrict__ bp,
                           float* __restrict__ out, int Eo) {
    int e = blockIdx.x * blockDim.x + threadIdx.x;
    if (e >= Eo) return;
    float acc = psrc[ei[e]] + pdst[ei[Eo + e]] + bp[0];
    float sg = 1.f / (1.f + __expf(-acc));
    out[e] = sg * 4.f + 1.f;
}

extern "C" void kernel_launch(void* const* d_in, const int* in_sizes, int n_in,
                              void* d_out, int out_size, void* d_ws, size_t ws_size,
                              hipStream_t stream) {
    const float* x   = (const float*)d_in[0];
    const int*   ei  = (const int*)  d_in[1];
    const float* W1  = (const float*)d_in[2];
    const float* as1 = (const float*)d_in[3];
    const float* ad1 = (const float*)d_in[4];
    const float* b1  = (const float*)d_in[5];
    const float* W2  = (const float*)d_in[6];
    const float* as2 = (const float*)d_in[7];
    const float* ad2 = (const float*)d_in[8];
    const float* b2  = (const float*)d_in[9];
    const float* W3  = (const float*)d_in[10];
    const float* as3 = (const float*)d_in[11];
    const float* ad3 = (const float*)d_in[12];
    const float* b3  = (const float*)d_in[13];
    const float* Wp  = (const float*)d_in[14];
    const float* bp  = (const float*)d_in[15];
    float* outp = (float*)d_out;

    const int n    = in_sizes[0] / 128;   // 50000
    const int Eo   = in_sizes[1] / 2;     // 800000
    const int Eext = Eo + n;              // 850000

    char* base = (char*)d_ws;
    unsigned short* hAb = (unsigned short*)base;   base += (size_t)n * 256 * 2;
    unsigned short* hBb = (unsigned short*)base;   base += (size_t)n * 256 * 2;
    unsigned short* Xb  = (unsigned short*)base;   base += (size_t)n * 128 * 2;
    unsigned short* Wl1 = (unsigned short*)base;   base += (size_t)128 * 256 * 2;
    unsigned short* Wl2 = (unsigned short*)base;   base += (size_t)256 * 128 * 2;
    unsigned short* Wl3 = (unsigned short*)base;   base += (size_t)128 * 32 * 2;
    float* esrc   = (float*)base;                  base += (size_t)n * 8 * 4;
    float* edst   = (float*)base;                  base += (size_t)n * 8 * 4;
    float* psrc   = (float*)base;                  base += (size_t)n * 4;
    float* pdst   = (float*)base;                  base += (size_t)n * 4;
    int* cnt      = (int*)base;                    base += (size_t)n * 4;
    unsigned int* gmaxb = (unsigned int*)base;     base += 16;      // zeroed with cnt
    int* rowptr   = (int*)base;                    base += (size_t)n * 4;
    int* cursors  = (int*)base;                    base += (size_t)n * 4;
    int* csr      = (int*)base;                    base += (size_t)Eext * 4;
    int* csr_src  = (int*)base;                    base += (size_t)Eext * 4;
    int* bsum     = (int*)base;

    const int TB = 256;
    auto nb = [](int tot, int tb) { return (tot + tb - 1) / tb; };

    // ---------------- CSR build (dst-sorted) + prep ----------------
    hipMemsetAsync(cnt, 0, (size_t)n * 4 + 16, stream);   // cnt + gmaxb
    hist_k<<<nb(Eext, TB), TB, 0, stream>>>(ei, cnt, Eo, Eext);
    int nChunks = (n + 1023) / 1024;
    scan1_k<<<nChunks, 256, 0, stream>>>(cnt, rowptr, bsum, n);
    scan2_k<<<1, 64, 0, stream>>>(bsum, nChunks);
    scan3_k<<<nb(n, TB), TB, 0, stream>>>(rowptr, cursors, bsum, n);
    scatter_k<<<nb(Eext, TB), TB, 0, stream>>>(ei, cursors, csr, Eo, Eext);
    sort_k<<<nb(n, TB), TB, 0, stream>>>(rowptr, cnt, csr, ei, csr_src, n, Eo);
    int prep_total = n * 32 + 4096 + 4096 + 512;
    prep_all_k<<<nb(prep_total, TB), TB, 0, stream>>>(x, Xb, W1, Wl1, W2, Wl2, W3, Wl3, n * 32);

    // ---------------- Layer 1: K=128, H=8, HC=256 ----------------
    gemm_mfma<128, 256, 8><<<nb(n, 128), 256, 0, stream>>>(Xb, Wl1, as1, ad1, hAb, esrc, edst, gmaxb + 0, n);
    aggr_fused<256, 8, false><<<nb(n * 32, TB), TB, 0, stream>>>(rowptr, cnt, csr_src, esrc, edst, gmaxb + 0,
                                                                 hAb, b1, hBb, nullptr, nullptr, nullptr, n);

    // ---------------- Layer 2: K=256, H=4, HC=128 ----------------
    gemm_mfma<256, 128, 4><<<nb(n, 128), 256, 0, stream>>>(hBb, Wl2, as2, ad2, hAb, esrc, edst, gmaxb + 1, n);
    aggr_fused<128, 4, false><<<nb(n * 16, TB), TB, 0, stream>>>(rowptr, cnt, csr_src, esrc, edst, gmaxb + 1,
                                                                 hAb, b2, hBb, nullptr, nullptr, nullptr, n);

    // ---------------- Layer 3: K=128, H=1, HC=32 (fused rank-1 predictor dots) ----------------
    gemm_mfma<128, 32, 1><<<nb(n, 128), 256, 0, stream>>>(hBb, Wl3, as3, ad3, hAb, esrc, edst, gmaxb + 2, n);
    aggr_fused<32, 1, true><<<nb(n * 4, TB), TB, 0, stream>>>(rowptr, cnt, csr_src, esrc, edst, gmaxb + 2,
                                                              hAb, b3, nullptr, psrc, pdst, Wp, n);

    // ---------------- predictor ----------------
    predict2_k<<<nb(Eo, TB), TB, 0, stream>>>(ei, psrc, pdst, bp, outp, Eo);
}